// Round 5
// baseline (44442.471 us; speedup 1.0000x reference)
//
#include <hip/hip_runtime.h>
#include <hip/hip_cooperative_groups.h>

namespace cg = cooperative_groups;

#define DEVFN __device__ __forceinline__

constexpr int V=32000, E=512, H=512, B=16, K=8, S=50, T=40, N=128;
constexpr int SOS=2, EOS=3, UNK=0, PAD=1, MIN_LEN=3;
constexpr float DD=0.1f;
constexpr float FNEG=-1e20f;

constexpr long long PROBS_ELEMS = 163840000LL; // T*N*V
constexpr int TOK_OUT_OFF = 163840000;
constexpr int BS_OUT_OFF  = 163845120;

// scratch offsets (floats) inside d_out's probs region (re-zeroed at the end)
constexpr int LOGITS_O = 0;          // N*V = 4,096,000
constexpr int WTOUT_O  = 4200000;    // 512*32000
constexpr int WTEIH_O  = 20600000;   // 512*1536
constexpr int WTEHH_O  = 21400000;
constexpr int WTDIH_O  = 22200000;
constexpr int WTDHH_O  = 23000000;
constexpr int WTATT_O  = 23800000;   // 512*512
constexpr int WTCMB_O  = 24100000;   // 1024*512
constexpr int WTBRG_O  = 24700000;   // 512*512
constexpr int ENC_O    = 25000000;   // S*B*H
constexpr int HST_O    = 25500000;   // 2*B*H
constexpr int HID_O    = 25520000;   // N*H
constexpr int HNEW_O   = 25600000;   // N*H
constexpr int CTX_O    = 25680000;   // N*H
constexpr int OVEC_O   = 25760000;   // N*H
constexpr int QVEC_O   = 25840000;   // N*H
constexpr int TKSC_O   = 25920000;   // N*K
constexpr int TKIX_O   = 25930000;   // N*K ints
constexpr int TOK0_O   = 25940000;   // T*N ints
constexpr int TOK1_O   = 25950000;
constexpr int BS0_O    = 25960000;   // T*N floats
constexpr int BS1_O    = 25970000;
constexpr int END_O    = 25980000;   // N ints
constexpr int LTOK_O   = 25990000;   // N ints

DEVFN float sigm(float x){ return 1.0f/(1.0f + expf(-x)); }

// ---------------- transpose: in[R][C] -> out[C][R] ----------------
__global__ void tr_k(const float* __restrict__ in, float* __restrict__ out, int R, int C){
  __shared__ float t[32][33];
  int bx = blockIdx.x, by = blockIdx.y;
  int x = threadIdx.x & 31, y0 = threadIdx.x >> 5;
  for (int yy = y0; yy < 32; yy += 8){
    t[yy][x] = in[(long long)(by*32+yy)*C + bx*32 + x];
  }
  __syncthreads();
  for (int yy = y0; yy < 32; yy += 8){
    out[(long long)(bx*32+yy)*R + by*32 + x] = t[x][yy];
  }
}

// ---------------- init ----------------
__global__ void init_k(float* sc){
  int idx = blockIdx.x*256 + threadIdx.x;
  int* tok0 = (int*)(sc + TOK0_O);
  float* bs0 = sc + BS0_O;
  if (idx < T*N){
    tok0[idx] = (idx < N) ? SOS : 0;
    bs0[idx]  = (idx < N && (idx & 7)) ? FNEG : 0.0f;
  }
  if (idx < N){
    ((int*)(sc + END_O))[idx] = 0;
    ((int*)(sc + LTOK_O))[idx] = SOS;
  }
  if (idx < 2*B*H) sc[HST_O + idx] = 0.0f;
}

// ================== THE MEGA KERNEL (cooperative) ==================
// 256 blocks x 256 threads, exactly 32KB LDS (2 blocks/CU headroom for the
// cooperative occupancy check). Phase bodies = round-3 kernels verbatim.
__global__ __launch_bounds__(256) void mega_k(
    const int* src, const int* srclen, const float* embed,
    const float* ebih, const float* ebhh, const float* brb,
    const float* dbih, const float* dbhh, const float* cmbb, const float* outb,
    float* sc){
  cg::grid_group grid = cg::this_grid();
  const int bid = blockIdx.x;
  const int tid = threadIdx.x;
  __shared__ __align__(16) float shm[8192];   // exactly 32 KB

  // ---------------- encoder loop ----------------
  {
    const float* wtih = sc + WTEIH_O;
    const float* wthh = sc + WTEHH_O;
    for (int t=0; t<S; t++){
      if (bid < 32){
        int b = bid & 15;
        int i = (bid >> 4)*256 + tid;
        float* e  = shm;          // 512
        float* hp = shm + 512;    // 512
        const float* hsrc = sc + HST_O + (t&1)*B*H + b*H;
        float* hdst = sc + HST_O + (((t&1)^1))*B*H + b*H;
        int tok = src[t*B + b];
        ((float2*)e)[tid]  = ((const float2*)(embed + (long long)tok*E))[tid];
        ((float2*)hp)[tid] = ((const float2*)hsrc)[tid];
        __syncthreads();
        float ar=0,az=0,an=0,hr=0,hz=0,hn=0;
        for (int k=0;k<512;k++){
          float ev = e[k], hv = hp[k];
          const float* wi = wtih + (long long)k*1536;
          const float* wh = wthh + (long long)k*1536;
          ar += ev*wi[i];      az += ev*wi[512+i];  an += ev*wi[1024+i];
          hr += hv*wh[i];      hz += hv*wh[512+i];  hn += hv*wh[1024+i];
        }
        float r = sigm(ar + ebih[i] + hr + ebhh[i]);
        float z = sigm(az + ebih[512+i] + hz + ebhh[512+i]);
        float nn = tanhf(an + ebih[1024+i] + r*(hn + ebhh[1024+i]));
        float hnew = (1.0f - z)*nn + z*hp[i];
        float hout = (t < srclen[b]) ? hnew : hp[i];
        hdst[i] = hout;
        sc[ENC_O + ((long long)t*B + b)*H + i] = hout;
      }
      grid.sync();
    }
  }

  // ---------------- bridge ----------------
  if (bid < 16){
    int b = bid;
    const float* wtb = sc + WTBRG_O;
    float* hf = shm;   // 512
    const float* hsrc = sc + HST_O + (S&1)*B*H + b*H;
    ((float2*)hf)[tid] = ((const float2*)hsrc)[tid];
    __syncthreads();
    for (int ii=0; ii<2; ii++){
      int i = tid + ii*256;
      float acc = brb[i];
      for (int k=0;k<512;k++) acc += hf[k]*wtb[(long long)k*512 + i];
      float hb = tanhf(acc);
      for (int q=0;q<K;q++) sc[HID_O + ((long long)(b*K+q))*H + i] = hb;
    }
  }
  grid.sync();

  // ---------------- decode loop ----------------
  for (int t=1; t<T; t++){
    // ---- phase: decoder GRU ----
    if (bid < 128){
      const float* wtih = sc + WTDIH_O;
      const float* wthh = sc + WTDHH_O;
      int il = tid & 63, sub = tid >> 6;
      int i = (bid & 7)*64 + il;
      int nb = (bid >> 3)*8;
      float* e8  = shm;          // [8][512]
      float* hp8 = shm + 4096;   // [8][512]
      const int* ltok = (const int*)(sc + LTOK_O);
      for (int u = tid; u < 8*128; u += 256){
        int r = u >> 7, c = u & 127;
        ((float4*)(e8 + r*512))[c]  = ((const float4*)(embed + (long long)ltok[nb+r]*E))[c];
        ((float4*)(hp8 + r*512))[c] = ((const float4*)(sc + HID_O + (long long)(nb+r)*H))[c];
      }
      __syncthreads();
      int n0 = sub*2, n1 = sub*2+1;
      float a0r=0,a0z=0,a0n=0,h0r=0,h0z=0,h0n=0;
      float a1r=0,a1z=0,a1n=0,h1r=0,h1z=0,h1n=0;
      for (int k=0;k<512;k++){
        const float* wi = wtih + (long long)k*1536;
        const float* wh = wthh + (long long)k*1536;
        float wr=wi[i], wz=wi[512+i], wn=wi[1024+i];
        float ur=wh[i], uz=wh[512+i], un=wh[1024+i];
        float e0=e8[n0*512+k], e1=e8[n1*512+k], p0=hp8[n0*512+k], p1=hp8[n1*512+k];
        a0r+=e0*wr; a0z+=e0*wz; a0n+=e0*wn; h0r+=p0*ur; h0z+=p0*uz; h0n+=p0*un;
        a1r+=e1*wr; a1z+=e1*wz; a1n+=e1*wn; h1r+=p1*ur; h1z+=p1*uz; h1n+=p1*un;
      }
      float br=dbih[i], bz=dbih[512+i], bn=dbih[1024+i];
      float cr=dbhh[i], cz=dbhh[512+i], cn=dbhh[1024+i];
      {
        float r = sigm(a0r+br+h0r+cr);
        float z = sigm(a0z+bz+h0z+cz);
        float nn = tanhf(a0n+bn + r*(h0n+cn));
        sc[HNEW_O + (long long)(nb+n0)*H + i] = (1.0f-z)*nn + z*hp8[n0*512+i];
      }
      {
        float r = sigm(a1r+br+h1r+cr);
        float z = sigm(a1z+bz+h1z+cz);
        float nn = tanhf(a1n+bn + r*(h1n+cn));
        sc[HNEW_O + (long long)(nb+n1)*H + i] = (1.0f-z)*nn + z*hp8[n1*512+i];
      }
    }
    grid.sync();

    // ---- phase: q = h_new @ attn_W^T ----
    if (bid < 128){
      const float* wta = sc + WTATT_O;
      int il = tid & 63, sub = tid >> 6;
      int i = (bid & 7)*64 + il;
      int nb = (bid >> 3)*8;
      float* hn8 = shm;  // [8][512]
      for (int u = tid; u < 8*128; u += 256){
        int r = u>>7, c = u&127;
        ((float4*)(hn8 + r*512))[c] = ((const float4*)(sc + HNEW_O + (long long)(nb+r)*H))[c];
      }
      __syncthreads();
      int n0 = sub*2, n1 = n0+1;
      float a0=0, a1=0;
      for (int k=0;k<512;k++){
        float w = wta[(long long)k*512 + i];
        a0 += hn8[n0*512+k]*w; a1 += hn8[n1*512+k]*w;
      }
      sc[QVEC_O + (long long)(nb+n0)*H + i] = a0;
      sc[QVEC_O + (long long)(nb+n1)*H + i] = a1;
    }
    grid.sync();

    // ---- phase: attention ----
    if (bid < 128){
      int n = bid; int g = n >> 3;
      int lane = tid & 63, wave = tid >> 6;
      float* ql = shm;        // 512
      float* al = shm + 512;  // 64
      if (tid < 128) ((float4*)ql)[tid] = ((const float4*)(sc + QVEC_O + (long long)n*H))[tid];
      __syncthreads();
      const float* enc = sc + ENC_O;
      for (int s = wave; s < S; s += 4){
        const float* er = enc + ((long long)s*B + g)*H;
        float p = 0;
        #pragma unroll
        for (int j=0;j<8;j++) p += ql[lane + 64*j]*er[lane + 64*j];
        #pragma unroll
        for (int off=32; off; off>>=1) p += __shfl_xor(p, off, 64);
        if (lane==0) al[s] = p;
      }
      __syncthreads();
      if (wave==0){
        int len = srclen[g];
        float v = (lane < S && lane < len) ? al[lane] : -1e9f;
        float m = v;
        #pragma unroll
        for (int off=32; off; off>>=1) m = fmaxf(m, __shfl_xor(m, off, 64));
        float ee = (lane < S) ? expf(v - m) : 0.0f;
        float ssum = ee;
        #pragma unroll
        for (int off=32; off; off>>=1) ssum += __shfl_xor(ssum, off, 64);
        if (lane < S) al[lane] = ee/ssum;
      }
      __syncthreads();
      for (int ii=0; ii<2; ii++){
        int i = tid + ii*256;
        float acc = 0;
        for (int s=0;s<S;s++) acc += al[s]*enc[((long long)s*B+g)*H + i];
        sc[CTX_O + (long long)n*H + i] = acc;
      }
    }
    grid.sync();

    // ---- phase: comb ----
    if (bid < 128){
      const float* wtc = sc + WTCMB_O;
      int il = tid & 63, sub = tid >> 6;
      int i = (bid & 7)*64 + il;
      int nb = (bid >> 3)*8;
      float* hn8 = shm;          // [8][512]
      float* cx8 = shm + 4096;   // [8][512]
      for (int u = tid; u < 8*128; u += 256){
        int r = u>>7, c = u&127;
        ((float4*)(hn8 + r*512))[c] = ((const float4*)(sc + HNEW_O + (long long)(nb+r)*H))[c];
        ((float4*)(cx8 + r*512))[c] = ((const float4*)(sc + CTX_O + (long long)(nb+r)*H))[c];
      }
      __syncthreads();
      int n0 = sub*2, n1 = n0+1;
      float a0=cmbb[i], a1=cmbb[i];
      for (int k=0;k<512;k++){
        float w = wtc[(long long)k*512 + i];
        a0 += hn8[n0*512+k]*w; a1 += hn8[n1*512+k]*w;
      }
      for (int k=0;k<512;k++){
        float w = wtc[(long long)(512+k)*512 + i];
        a0 += cx8[n0*512+k]*w; a1 += cx8[n1*512+k]*w;
      }
      sc[OVEC_O + (long long)(nb+n0)*H + i] = tanhf(a0);
      sc[OVEC_O + (long long)(nb+n1)*H + i] = tanhf(a1);
    }
    grid.sync();

    // ---- phase: logits (all 256 blocks) ----
    {
      const float* wto = sc + WTOUT_O;
      int v = (bid & 31)*1024 + tid*4;
      int nb = (bid >> 5)*16;
      float* o16 = shm;  // [16][512] = 8192
      for (int u = tid; u < 16*128; u += 256){
        int r = u>>7, c = u&127;
        ((float4*)(o16 + r*512))[c] = ((const float4*)(sc + OVEC_O + (long long)(nb + r)*H))[c];
      }
      __syncthreads();
      if (v < V){
        float acc[16][4] = {};
        const float* wp = wto + v;
        for (int k=0;k<512;k+=4){
          float4 w0 = *((const float4*)(wp + (long long)(k+0)*V));
          float4 w1 = *((const float4*)(wp + (long long)(k+1)*V));
          float4 w2 = *((const float4*)(wp + (long long)(k+2)*V));
          float4 w3 = *((const float4*)(wp + (long long)(k+3)*V));
          #pragma unroll
          for (int j=0;j<16;j++){
            float4 o = *((const float4*)&o16[j*512 + k]);
            acc[j][0] += o.x*w0.x + o.y*w1.x + o.z*w2.x + o.w*w3.x;
            acc[j][1] += o.x*w0.y + o.y*w1.y + o.z*w2.y + o.w*w3.y;
            acc[j][2] += o.x*w0.z + o.y*w1.z + o.z*w2.z + o.w*w3.z;
            acc[j][3] += o.x*w0.w + o.y*w1.w + o.z*w2.w + o.w*w3.w;
          }
        }
        float4 bbv = *((const float4*)(outb + v));
        #pragma unroll
        for (int j=0;j<16;j++){
          float4 r;
          r.x = acc[j][0]+bbv.x; r.y = acc[j][1]+bbv.y; r.z = acc[j][2]+bbv.z; r.w = acc[j][3]+bbv.w;
          *((float4*)(sc + LOGITS_O + (long long)(nb+j)*V + v)) = r;
        }
      }
    }
    grid.sync();

    // ---- phase: topk ----
    if (bid < 128){
      int n = bid;
      const float4* row4 = (const float4*)(sc + LOGITS_O + (long long)n*V);
      float* rv = shm;                    // 256
      float* mv = shm + 256;              // [256][8]
      int*   mi = (int*)(shm + 2304);     // [256][8]
      float lm = -INFINITY;
      for (int u = tid; u < V/4; u += 256){
        float4 x = row4[u];
        lm = fmaxf(lm, fmaxf(fmaxf(x.x,x.y), fmaxf(x.z,x.w)));
      }
      rv[tid] = lm; __syncthreads();
      for (int s2=128; s2; s2>>=1){ if (tid<s2) rv[tid]=fmaxf(rv[tid],rv[tid+s2]); __syncthreads(); }
      float rmax = rv[0]; __syncthreads();
      float tv[8]; int ti[8];
      #pragma unroll
      for (int j=0;j<8;j++){ tv[j] = -INFINITY; ti[j] = V; }
      float ls = 0;
      for (int u = tid; u < V/4; u += 256){
        float4 x = row4[u];
        ls += expf(x.x-rmax)+expf(x.y-rmax)+expf(x.z-rmax)+expf(x.w-rmax);
        #pragma unroll
        for (int c=0;c<4;c++){
          int idx = u*4+c;
          float val = (c==0)?x.x:(c==1)?x.y:(c==2)?x.z:x.w;
          bool masked = (idx==UNK) || (idx==EOS && t<=MIN_LEN);
          if (!masked && val > tv[7]){
            tv[7] = val; ti[7] = idx;
            #pragma unroll
            for (int j=7;j>0;j--){
              if (tv[j] > tv[j-1]){
                float tf=tv[j]; tv[j]=tv[j-1]; tv[j-1]=tf;
                int tii=ti[j]; ti[j]=ti[j-1]; ti[j-1]=tii;
              }
            }
          }
        }
      }
      rv[tid] = ls;
      #pragma unroll
      for (int j=0;j<8;j++){ mv[tid*8+j]=tv[j]; mi[tid*8+j]=ti[j]; }
      __syncthreads();
      for (int s2=128; s2; s2>>=1){ if (tid<s2) rv[tid]+=rv[tid+s2]; __syncthreads(); }
      float lsum = logf(rv[0]);
      for (int s2=128; s2; s2>>=1){
        if (tid < s2){
          float ra[8]; int ri_[8];
          int pa=0, pb=0;
          #pragma unroll
          for (int o=0;o<8;o++){
            float va = mv[tid*8 + (pa<8?pa:7)];        int xa = mi[tid*8 + (pa<8?pa:7)];
            float vb = mv[(tid+s2)*8 + (pb<8?pb:7)];   int xb = mi[(tid+s2)*8 + (pb<8?pb:7)];
            bool ava = (pa<8), avb = (pb<8);
            bool ta;
            if (!ava) ta = false;
            else if (!avb) ta = true;
            else ta = (va > vb) || (va == vb && xa < xb);
            ra[o] = ta ? va : vb; ri_[o] = ta ? xa : xb;
            pa += ta ? 1 : 0; pb += ta ? 0 : 1;
          }
          #pragma unroll
          for (int o=0;o<8;o++){ mv[tid*8+o]=ra[o]; mi[tid*8+o]=ri_[o]; }
        }
        __syncthreads();
      }
      if (tid < 8){
        sc[TKSC_O + n*8 + tid] = (mv[tid] - rmax) - lsum;
        ((int*)(sc + TKIX_O))[n*8 + tid] = mi[tid];
      }
    }
    grid.sync();

    // ---- phase: beam bookkeeping ----
    if (bid < 16){
      int b = bid;
      const float* tksc = sc + TKSC_O;
      const int* tkix = (const int*)(sc + TKIX_O);
      int* endp = (int*)(sc + END_O);
      int* ltok = (int*)(sc + LTOK_O);
      const int* tokc; int* tokn; const float* bsc; float* bsn;
      if (t & 1){ tokc=(const int*)(sc+TOK0_O); tokn=(int*)(sc+TOK1_O); bsc=sc+BS0_O; bsn=sc+BS1_O; }
      else      { tokc=(const int*)(sc+TOK1_O); tokn=(int*)(sc+TOK0_O); bsc=sc+BS1_O; bsn=sc+BS0_O; }
      float* tot = shm;             // 64
      float* cur = shm + 64;        // 64
      int*   tix = (int*)(shm+128); // 64
      int* selp   = (int*)(shm+192);
      int* newtok = (int*)(shm+200);
      float* newsc = shm+208;
      int* newend = (int*)(shm+216);
      if (tid == 0){
        for (int k=0;k<8;k++){
          float tp = 0;
          for (int u=0;u<T;u++) tp += bsc[u*N + b*8 + k];
          int ek = endp[b*8+k];
          for (int j=0;j<8;j++){
            float scv = tksc[(b*8+k)*8 + j];
            if (t > 1) scv -= DD * (float)j;
            float fin = ek ? (-scv + (j==0 ? 0.0f : FNEG)) : 0.0f;
            tot[k*8+j] = (scv + tp) + fin;
            cur[k*8+j] = scv + fin;
            tix[k*8+j] = tkix[(b*8+k)*8 + j];
          }
        }
        for (int q=0;q<8;q++){
          int best = 0; float bv = tot[0];
          for (int c=1;c<64;c++){
            if (tot[c] > bv){ bv = tot[c]; best = c; }
          }
          int p = best >> 3;
          int en = endp[b*8+p];
          int tk2 = tix[best];
          int lt = en ? PAD : tk2;
          selp[q] = p;
          newtok[q] = lt;
          newsc[q] = (lt != PAD) ? cur[best] : 0.0f;
          newend[q] = (en || lt == EOS) ? 1 : 0;
          tot[best] = -INFINITY;
        }
      }
      __syncthreads();
      for (int u = tid; u < T*8; u += 256){
        int tp2 = u >> 3, jp = u & 7;
        int p = selp[jp];
        tokn[tp2*N + b*8 + jp] = tokc[tp2*N + b*8 + p];
        bsn[tp2*N + b*8 + jp]  = bsc[tp2*N + b*8 + p];
      }
      __syncthreads();
      if (tid < 8){
        tokn[t*N + b*8 + tid] = newtok[tid];
        bsn[t*N + b*8 + tid]  = newsc[tid];
        ltok[b*8+tid] = newtok[tid];
        endp[b*8+tid] = newend[tid];
      }
      const float4* hsrc = (const float4*)(sc + HNEW_O + (long long)(b*8)*H);
      float4* hdst = (float4*)(sc + HID_O + (long long)(b*8)*H);
      for (int u = tid; u < 8*128; u += 256){
        int jp = u >> 7, c = u & 127;
        hdst[jp*128 + c] = hsrc[c];
      }
    }
    grid.sync();
  }
}

// ========== FALLBACK PATH (round-3 kernels, numerics identical) ==========
__global__ __launch_bounds__(256) void enc_k(const int* __restrict__ src, const int* __restrict__ srclen,
                      const float* __restrict__ embed,
                      const float* __restrict__ wtih, const float* __restrict__ wthh,
                      const float* __restrict__ bih, const float* __restrict__ bhh,
                      float* sc, int t){
  int b = blockIdx.x;
  int i = blockIdx.y*256 + threadIdx.x;
  __shared__ __align__(16) float e[512];
  __shared__ __align__(16) float hp[512];
  const float* hsrc = sc + HST_O + (t&1)*B*H + b*H;
  float* hdst = sc + HST_O + (((t&1)^1))*B*H + b*H;
  int tok = src[t*B + b];
  {
    int tid = threadIdx.x;
    ((float2*)e)[tid]  = ((const float2*)(embed + (long long)tok*E))[tid];
    ((float2*)hp)[tid] = ((const float2*)hsrc)[tid];
  }
  __syncthreads();
  float ar=0,az=0,an=0,hr=0,hz=0,hn=0;
  for (int k=0;k<512;k++){
    float ev = e[k], hv = hp[k];
    const float* wi = wtih + (long long)k*1536;
    const float* wh = wthh + (long long)k*1536;
    ar += ev*wi[i];      az += ev*wi[512+i];  an += ev*wi[1024+i];
    hr += hv*wh[i];      hz += hv*wh[512+i];  hn += hv*wh[1024+i];
  }
  float r = sigm(ar + bih[i] + hr + bhh[i]);
  float z = sigm(az + bih[512+i] + hz + bhh[512+i]);
  float nn = tanhf(an + bih[1024+i] + r*(hn + bhh[1024+i]));
  float hnew = (1.0f - z)*nn + z*hp[i];
  float hout = (t < srclen[b]) ? hnew : hp[i];
  hdst[i] = hout;
  sc[ENC_O + ((long long)t*B + b)*H + i] = hout;
}

__global__ __launch_bounds__(256) void bridge_k(const float* __restrict__ wtb, const float* __restrict__ bb, float* sc){
  int b = blockIdx.x; int tid = threadIdx.x;
  __shared__ __align__(16) float hf[512];
  const float* hsrc = sc + HST_O + (S&1)*B*H + b*H;
  ((float2*)hf)[tid] = ((const float2*)hsrc)[tid];
  __syncthreads();
  for (int ii=0; ii<2; ii++){
    int i = tid + ii*256;
    float acc = bb[i];
    for (int k=0;k<512;k++) acc += hf[k]*wtb[(long long)k*512 + i];
    float hb = tanhf(acc);
    for (int q=0;q<K;q++) sc[HID_O + ((long long)(b*K+q))*H + i] = hb;
  }
}

__global__ __launch_bounds__(256) void grudec_k(const float* __restrict__ embed,
     const float* __restrict__ wtih, const float* __restrict__ wthh,
     const float* __restrict__ bih, const float* __restrict__ bhh, float* sc){
  int il = threadIdx.x & 63, sub = threadIdx.x >> 6;
  int i = blockIdx.x*64 + il;
  int nb = blockIdx.y*8;
  __shared__ __align__(16) float e8[8][512];
  __shared__ __align__(16) float hp8[8][512];
  const int* ltok = (const int*)(sc + LTOK_O);
  for (int u = threadIdx.x; u < 8*128; u += 256){
    int r = u >> 7, c = u & 127;
    ((float4*)e8[r])[c]  = ((const float4*)(embed + (long long)ltok[nb+r]*E))[c];
    ((float4*)hp8[r])[c] = ((const float4*)(sc + HID_O + (long long)(nb+r)*H))[c];
  }
  __syncthreads();
  int n0 = sub*2, n1 = sub*2+1;
  float a0r=0,a0z=0,a0n=0,h0r=0,h0z=0,h0n=0;
  float a1r=0,a1z=0,a1n=0,h1r=0,h1z=0,h1n=0;
  for (int k=0;k<512;k++){
    const float* wi = wtih + (long long)k*1536;
    const float* wh = wthh + (long long)k*1536;
    float wr=wi[i], wz=wi[512+i], wn=wi[1024+i];
    float ur=wh[i], uz=wh[512+i], un=wh[1024+i];
    float e0=e8[n0][k], e1=e8[n1][k], p0=hp8[n0][k], p1=hp8[n1][k];
    a0r+=e0*wr; a0z+=e0*wz; a0n+=e0*wn; h0r+=p0*ur; h0z+=p0*uz; h0n+=p0*un;
    a1r+=e1*wr; a1z+=e1*wz; a1n+=e1*wn; h1r+=p1*ur; h1z+=p1*uz; h1n+=p1*un;
  }
  float br=bih[i], bz=bih[512+i], bn=bih[1024+i];
  float cr=bhh[i], cz=bhh[512+i], cn=bhh[1024+i];
  {
    float r = sigm(a0r+br+h0r+cr);
    float z = sigm(a0z+bz+h0z+cz);
    float nn = tanhf(a0n+bn + r*(h0n+cn));
    sc[HNEW_O + (long long)(nb+n0)*H + i] = (1.0f-z)*nn + z*hp8[n0][i];
  }
  {
    float r = sigm(a1r+br+h1r+cr);
    float z = sigm(a1z+bz+h1z+cz);
    float nn = tanhf(a1n+bn + r*(h1n+cn));
    sc[HNEW_O + (long long)(nb+n1)*H + i] = (1.0f-z)*nn + z*hp8[n1][i];
  }
}

__global__ __launch_bounds__(256) void qgemm_k(const float* __restrict__ wta, float* sc){
  int il = threadIdx.x & 63, sub = threadIdx.x >> 6;
  int i = blockIdx.x*64 + il;
  int nb = blockIdx.y*8;
  __shared__ __align__(16) float hn8[8][512];
  for (int u = threadIdx.x; u < 8*128; u += 256){
    int r = u>>7, c = u&127;
    ((float4*)hn8[r])[c] = ((const float4*)(sc + HNEW_O + (long long)(nb+r)*H))[c];
  }
  __syncthreads();
  int n0 = sub*2, n1 = n0+1;
  float a0=0, a1=0;
  for (int k=0;k<512;k++){
    float w = wta[(long long)k*512 + i];
    a0 += hn8[n0][k]*w; a1 += hn8[n1][k]*w;
  }
  sc[QVEC_O + (long long)(nb+n0)*H + i] = a0;
  sc[QVEC_O + (long long)(nb+n1)*H + i] = a1;
}

__global__ __launch_bounds__(256) void att_k(const int* __restrict__ srclen, float* sc){
  int n = blockIdx.x; int g = n >> 3;
  int tid = threadIdx.x, lane = tid & 63, wave = tid >> 6;
  __shared__ __align__(16) float ql[512];
  __shared__ float al[64];
  if (tid < 128) ((float4*)ql)[tid] = ((const float4*)(sc + QVEC_O + (long long)n*H))[tid];
  __syncthreads();
  const float* enc = sc + ENC_O;
  for (int s = wave; s < S; s += 4){
    const float* er = enc + ((long long)s*B + g)*H;
    float p = 0;
    #pragma unroll
    for (int j=0;j<8;j++) p += ql[lane + 64*j]*er[lane + 64*j];
    #pragma unroll
    for (int off=32; off; off>>=1) p += __shfl_xor(p, off, 64);
    if (lane==0) al[s] = p;
  }
  __syncthreads();
  if (wave==0){
    int len = srclen[g];
    float v = (lane < S && lane < len) ? al[lane] : -1e9f;
    float m = v;
    #pragma unroll
    for (int off=32; off; off>>=1) m = fmaxf(m, __shfl_xor(m, off, 64));
    float ee = (lane < S) ? expf(v - m) : 0.0f;
    float ssum = ee;
    #pragma unroll
    for (int off=32; off; off>>=1) ssum += __shfl_xor(ssum, off, 64);
    if (lane < S) al[lane] = ee/ssum;
  }
  __syncthreads();
  for (int ii=0; ii<2; ii++){
    int i = tid + ii*256;
    float acc = 0;
    for (int s=0;s<S;s++) acc += al[s]*enc[((long long)s*B+g)*H + i];
    sc[CTX_O + (long long)n*H + i] = acc;
  }
}

__global__ __launch_bounds__(256) void comb_k(const float* __restrict__ wtc, const float* __restrict__ cb, float* sc){
  int il = threadIdx.x & 63, sub = threadIdx.x >> 6;
  int i = blockIdx.x*64 + il;
  int nb = blockIdx.y*8;
  __shared__ __align__(16) float hn8[8][512];
  __shared__ __align__(16) float cx8[8][512];
  for (int u = threadIdx.x; u < 8*128; u += 256){
    int r = u>>7, c = u&127;
    ((float4*)hn8[r])[c] = ((const float4*)(sc + HNEW_O + (long long)(nb+r)*H))[c];
    ((float4*)cx8[r])[c] = ((const float4*)(sc + CTX_O + (long long)(nb+r)*H))[c];
  }
  __syncthreads();
  int n0 = sub*2, n1 = n0+1;
  float a0=cb[i], a1=cb[i];
  for (int k=0;k<512;k++){
    float w = wtc[(long long)k*512 + i];
    a0 += hn8[n0][k]*w; a1 += hn8[n1][k]*w;
  }
  for (int k=0;k<512;k++){
    float w = wtc[(long long)(512+k)*512 + i];
    a0 += cx8[n0][k]*w; a1 += cx8[n1][k]*w;
  }
  sc[OVEC_O + (long long)(nb+n0)*H + i] = tanhf(a0);
  sc[OVEC_O + (long long)(nb+n1)*H + i] = tanhf(a1);
}

__global__ __launch_bounds__(256) void logits_k(const float* __restrict__ wto, const float* __restrict__ ob, float* sc){
  int v = blockIdx.x*1024 + threadIdx.x*4;
  int nb = blockIdx.y*16;
  __shared__ __align__(16) float o16[16][512];
  for (int u = threadIdx.x; u < 16*128; u += 256){
    int r = u>>7, c = u&127;
    ((float4*)o16[r])[c] = ((const float4*)(sc + OVEC_O + (long long)(nb + r)*H))[c];
  }
  __syncthreads();
  if (v >= V) return;
  float acc[16][4] = {};
  const float* wp = wto + v;
  for (int k=0;k<512;k+=4){
    float4 w0 = *((const float4*)(wp + (long long)(k+0)*V));
    float4 w1 = *((const float4*)(wp + (long long)(k+1)*V));
    float4 w2 = *((const float4*)(wp + (long long)(k+2)*V));
    float4 w3 = *((const float4*)(wp + (long long)(k+3)*V));
    #pragma unroll
    for (int j=0;j<16;j++){
      float4 o = *((const float4*)&o16[j][k]);
      acc[j][0] += o.x*w0.x + o.y*w1.x + o.z*w2.x + o.w*w3.x;
      acc[j][1] += o.x*w0.y + o.y*w1.y + o.z*w2.y + o.w*w3.y;
      acc[j][2] += o.x*w0.z + o.y*w1.z + o.z*w2.z + o.w*w3.z;
      acc[j][3] += o.x*w0.w + o.y*w1.w + o.z*w2.w + o.w*w3.w;
    }
  }
  float4 bbv = *((const float4*)(ob + v));
  #pragma unroll
  for (int j=0;j<16;j++){
    float4 r;
    r.x = acc[j][0]+bbv.x; r.y = acc[j][1]+bbv.y; r.z = acc[j][2]+bbv.z; r.w = acc[j][3]+bbv.w;
    *((float4*)(sc + LOGITS_O + (long long)(nb+j)*V + v)) = r;
  }
}

__global__ __launch_bounds__(256) void topk_k(float* sc, int t){
  int n = blockIdx.x, tid = threadIdx.x;
  const float4* row4 = (const float4*)(sc + LOGITS_O + (long long)n*V);
  __shared__ float rv[256];
  __shared__ float mv[256][8];
  __shared__ int   mi[256][8];
  float lm = -INFINITY;
  for (int u = tid; u < V/4; u += 256){
    float4 x = row4[u];
    lm = fmaxf(lm, fmaxf(fmaxf(x.x,x.y), fmaxf(x.z,x.w)));
  }
  rv[tid] = lm; __syncthreads();
  for (int s2=128; s2; s2>>=1){ if (tid<s2) rv[tid]=fmaxf(rv[tid],rv[tid+s2]); __syncthreads(); }
  float rmax = rv[0]; __syncthreads();
  float tv[8]; int ti[8];
  #pragma unroll
  for (int j=0;j<8;j++){ tv[j] = -INFINITY; ti[j] = V; }
  float ls = 0;
  for (int u = tid; u < V/4; u += 256){
    float4 x = row4[u];
    ls += expf(x.x-rmax)+expf(x.y-rmax)+expf(x.z-rmax)+expf(x.w-rmax);
    #pragma unroll
    for (int c=0;c<4;c++){
      int idx = u*4+c;
      float val = (c==0)?x.x:(c==1)?x.y:(c==2)?x.z:x.w;
      bool masked = (idx==UNK) || (idx==EOS && t<=MIN_LEN);
      if (!masked && val > tv[7]){
        tv[7] = val; ti[7] = idx;
        #pragma unroll
        for (int j=7;j>0;j--){
          if (tv[j] > tv[j-1]){
            float tf=tv[j]; tv[j]=tv[j-1]; tv[j-1]=tf;
            int tii=ti[j]; ti[j]=ti[j-1]; ti[j-1]=tii;
          }
        }
      }
    }
  }
  rv[tid] = ls;
  #pragma unroll
  for (int j=0;j<8;j++){ mv[tid][j]=tv[j]; mi[tid][j]=ti[j]; }
  __syncthreads();
  for (int s2=128; s2; s2>>=1){ if (tid<s2) rv[tid]+=rv[tid+s2]; __syncthreads(); }
  float lsum = logf(rv[0]);
  for (int s2=128; s2; s2>>=1){
    if (tid < s2){
      float ra[8]; int ri_[8];
      int pa=0, pb=0;
      #pragma unroll
      for (int o=0;o<8;o++){
        float va = mv[tid][pa<8?pa:7];   int xa = mi[tid][pa<8?pa:7];
        float vb = mv[tid+s2][pb<8?pb:7]; int xb = mi[tid+s2][pb<8?pb:7];
        bool ava = (pa<8), avb = (pb<8);
        bool ta;
        if (!ava) ta = false;
        else if (!avb) ta = true;
        else ta = (va > vb) || (va == vb && xa < xb);
        ra[o] = ta ? va : vb; ri_[o] = ta ? xa : xb;
        pa += ta ? 1 : 0; pb += ta ? 0 : 1;
      }
      #pragma unroll
      for (int o=0;o<8;o++){ mv[tid][o]=ra[o]; mi[tid][o]=ri_[o]; }
    }
    __syncthreads();
  }
  if (tid < 8){
    sc[TKSC_O + n*8 + tid] = (mv[0][tid] - rmax) - lsum;
    ((int*)(sc + TKIX_O))[n*8 + tid] = mi[0][tid];
  }
}

__global__ __launch_bounds__(64) void beam_k(float* sc, int t){
  int b = blockIdx.x, lane = threadIdx.x;
  const float* tksc = sc + TKSC_O;
  const int* tkix = (const int*)(sc + TKIX_O);
  int* endp = (int*)(sc + END_O);
  int* ltok = (int*)(sc + LTOK_O);
  const int* tokc; int* tokn; const float* bsc; float* bsn;
  if (t & 1){ tokc=(const int*)(sc+TOK0_O); tokn=(int*)(sc+TOK1_O); bsc=sc+BS0_O; bsn=sc+BS1_O; }
  else      { tokc=(const int*)(sc+TOK1_O); tokn=(int*)(sc+TOK0_O); bsc=sc+BS1_O; bsn=sc+BS0_O; }
  __shared__ int selp[8]; __shared__ int newtok[8]; __shared__ float newsc[8]; __shared__ int newend[8];
  if (lane == 0){
    float tot[64]; float cur[64]; int tix[64];
    for (int k=0;k<8;k++){
      float tp = 0;
      for (int u=0;u<T;u++) tp += bsc[u*N + b*8 + k];
      int ek = endp[b*8+k];
      for (int j=0;j<8;j++){
        float scv = tksc[(b*8+k)*8 + j];
        if (t > 1) scv -= DD * (float)j;
        float fin = ek ? (-scv + (j==0 ? 0.0f : FNEG)) : 0.0f;
        tot[k*8+j] = (scv + tp) + fin;
        cur[k*8+j] = scv + fin;
        tix[k*8+j] = tkix[(b*8+k)*8 + j];
      }
    }
    for (int q=0;q<8;q++){
      int best = 0; float bv = tot[0];
      for (int c=1;c<64;c++){
        if (tot[c] > bv){ bv = tot[c]; best = c; }
      }
      int p = best >> 3;
      int en = endp[b*8+p];
      int tk2 = tix[best];
      int lt = en ? PAD : tk2;
      selp[q] = p;
      newtok[q] = lt;
      newsc[q] = (lt != PAD) ? cur[best] : 0.0f;
      newend[q] = (en || lt == EOS) ? 1 : 0;
      tot[best] = -INFINITY;
    }
  }
  __syncthreads();
  for (int u = lane; u < T*8; u += 64){
    int tp2 = u >> 3, jp = u & 7;
    int p = selp[jp];
    tokn[tp2*N + b*8 + jp] = tokc[tp2*N + b*8 + p];
    bsn[tp2*N + b*8 + jp]  = bsc[tp2*N + b*8 + p];
  }
  __syncthreads();
  if (lane < 8){
    tokn[t*N + b*8 + lane] = newtok[lane];
    bsn[t*N + b*8 + lane]  = newsc[lane];
    ltok[b*8+lane] = newtok[lane];
    endp[b*8+lane] = newend[lane];
  }
  const float4* hsrc = (const float4*)(sc + HNEW_O + (long long)(b*8)*H);
  float4* hdst = (float4*)(sc + HID_O + (long long)(b*8)*H);
  for (int u = lane; u < 8*128; u += 64){
    int jp = u >> 7, c = u & 127;
    hdst[jp*128 + c] = hsrc[c];
  }
}

// ---------------- emit tokens (as float) + beam_scores ----------------
__global__ void emit_k(float* out, float* sc){
  int idx = blockIdx.x*256 + threadIdx.x;
  if (idx < T*N){
    out[TOK_OUT_OFF + idx] = (float)(((const int*)(sc + TOK1_O))[idx]);
    out[BS_OUT_OFF + idx]  = sc[BS1_O + idx];
  }
}

extern "C" void kernel_launch(void* const* d_in, const int* in_sizes, int n_in,
                              void* d_out, int out_size, void* d_ws, size_t ws_size,
                              hipStream_t stream){
  const int*   src    = (const int*)d_in[0];
  const int*   srclen = (const int*)d_in[1];
  const float* embed  = (const float*)d_in[2];
  const float* eWih   = (const float*)d_in[3];
  const float* eWhh   = (const float*)d_in[4];
  const float* ebih   = (const float*)d_in[5];
  const float* ebhh   = (const float*)d_in[6];
  const float* brW    = (const float*)d_in[7];
  const float* brb    = (const float*)d_in[8];
  const float* dWih   = (const float*)d_in[9];
  const float* dWhh   = (const float*)d_in[10];
  const float* dbih   = (const float*)d_in[11];
  const float* dbhh   = (const float*)d_in[12];
  const float* attW   = (const float*)d_in[13];
  const float* cmbW   = (const float*)d_in[14];
  const float* cmbb   = (const float*)d_in[15];
  const float* outW   = (const float*)d_in[16];
  const float* outb   = (const float*)d_in[17];
  float* sc = (float*)d_out;

  tr_k<<<dim3(16,48),256,0,stream>>>(eWih, sc+WTEIH_O, 1536, 512);
  tr_k<<<dim3(16,48),256,0,stream>>>(eWhh, sc+WTEHH_O, 1536, 512);
  tr_k<<<dim3(16,48),256,0,stream>>>(dWih, sc+WTDIH_O, 1536, 512);
  tr_k<<<dim3(16,48),256,0,stream>>>(dWhh, sc+WTDHH_O, 1536, 512);
  tr_k<<<dim3(16,16),256,0,stream>>>(attW, sc+WTATT_O, 512, 512);
  tr_k<<<dim3(32,16),256,0,stream>>>(cmbW, sc+WTCMB_O, 512, 1024);
  tr_k<<<dim3(16,16),256,0,stream>>>(brW,  sc+WTBRG_O, 512, 512);
  tr_k<<<dim3(16,1000),256,0,stream>>>(outW, sc+WTOUT_O, 32000, 512);
  init_k<<<64,256,0,stream>>>(sc);

  hipError_t cerr;
  {
    void* args[] = {
      (void*)&src, (void*)&srclen, (void*)&embed,
      (void*)&ebih, (void*)&ebhh, (void*)&brb,
      (void*)&dbih, (void*)&dbhh, (void*)&cmbb, (void*)&outb,
      (void*)&sc
    };
    cerr = hipLaunchCooperativeKernel((const void*)mega_k, dim3(256), dim3(256),
                                      args, 0, stream);
  }
  if (cerr != hipSuccess){
    // fallback: proven multi-kernel sequence (bit-identical numerics)
    for (int t=0; t<S; t++)
      enc_k<<<dim3(16,2),256,0,stream>>>(src, srclen, embed, sc+WTEIH_O, sc+WTEHH_O, ebih, ebhh, sc, t);
    bridge_k<<<16,256,0,stream>>>(sc+WTBRG_O, brb, sc);
    for (int t=1; t<T; t++){
      grudec_k<<<dim3(8,16),256,0,stream>>>(embed, sc+WTDIH_O, sc+WTDHH_O, dbih, dbhh, sc);
      qgemm_k<<<dim3(8,16),256,0,stream>>>(sc+WTATT_O, sc);
      att_k<<<128,256,0,stream>>>(srclen, sc);
      comb_k<<<dim3(8,16),256,0,stream>>>(sc+WTCMB_O, cmbb, sc);
      logits_k<<<dim3(32,8),256,0,stream>>>(sc+WTOUT_O, outb, sc);
      topk_k<<<128,256,0,stream>>>(sc, t);
      beam_k<<<16,64,0,stream>>>(sc, t);
    }
  }

  emit_k<<<20,256,0,stream>>>((float*)d_out, sc);
  hipMemsetAsync(d_out, 0, (size_t)PROBS_ELEMS*4, stream);
}

// Round 6
// 19427.733 us; speedup vs baseline: 2.2876x; 2.2876x over previous
//
#include <hip/hip_runtime.h>

#define DEVFN __device__ __forceinline__

constexpr int V=32000, E=512, H=512, B=16, K=8, S=50, T=40, N=128;
constexpr int SOS=2, EOS=3, UNK=0, PAD=1, MIN_LEN=3;
constexpr float DD=0.1f;
constexpr float FNEG=-1e20f;

constexpr long long PROBS_ELEMS = 163840000LL; // T*N*V
constexpr int TOK_OUT_OFF = 163840000;
constexpr int BS_OUT_OFF  = 163845120;

// scratch offsets (floats) inside d_out's probs region (re-zeroed at the end)
constexpr int LOGITS_O = 0;          // N*V
constexpr int WTOUT_O  = 4200000;    // 512*32000
constexpr int WTEIH_O  = 20600000;   // [512][1536]
constexpr int WTEHH_O  = 21400000;
constexpr int WTDIH_O  = 22200000;
constexpr int WTDHH_O  = 23000000;
constexpr int WTATT_O  = 23800000;   // [512][512]
constexpr int WTCMB_O  = 24100000;   // [1024][512]
constexpr int WTBRG_O  = 24700000;   // [512][512]
constexpr int ENC_O    = 25000000;   // S*B*H
constexpr int HST_O    = 25500000;   // 2*B*H (encoder h ping-pong)
constexpr int HN0_O    = 25520000;   // N*H  (decoder h, parity 0)
constexpr int HN1_O    = 25600000;   // N*H  (decoder h, parity 1)
constexpr int OVEC_O   = 25760000;   // N*H
constexpr int TKSC_O   = 25920000;   // N*K
constexpr int TKIX_O   = 25930000;   // N*K ints
constexpr int TOK0_O   = 25940000;   // T*N ints (state parity 0)
constexpr int TOK1_O   = 25950000;   // T*N ints (state parity 1)
constexpr int BS0_O    = 25960000;   // T*N floats
constexpr int BS1_O    = 25970000;
constexpr int END0_O   = 25980000;   // N ints
constexpr int END1_O   = 25984000;   // N ints

DEVFN float sigm(float x){ return 1.0f/(1.0f + expf(-x)); }

// ---------------- transpose: in[R][C] -> out[C][R] ----------------
__global__ void tr_k(const float* __restrict__ in, float* __restrict__ out, int R, int C){
  __shared__ float t[32][33];
  int bx = blockIdx.x, by = blockIdx.y;
  int x = threadIdx.x & 31, y0 = threadIdx.x >> 5;
  for (int yy = y0; yy < 32; yy += 8){
    t[yy][x] = in[(long long)(by*32+yy)*C + bx*32 + x];
  }
  __syncthreads();
  for (int yy = y0; yy < 32; yy += 8){
    out[(long long)(bx*32+yy)*R + by*32 + x] = t[x][yy];
  }
}

// ---------------- init ----------------
__global__ void init_k(float* sc){
  int idx = blockIdx.x*256 + threadIdx.x;
  int* tok0 = (int*)(sc + TOK0_O);
  float* bs0 = sc + BS0_O;
  if (idx < T*N){
    tok0[idx] = (idx < N) ? SOS : 0;
    bs0[idx]  = (idx < N && (idx & 7)) ? FNEG : 0.0f;
  }
  if (idx < N) ((int*)(sc + END0_O))[idx] = 0;
  if (idx < 2*B*H) sc[HST_O + idx] = 0.0f;
}

// ---------------- encoder one step: 128 blocks (8 i-chunks x 16 batches), 384 thr ----------------
__global__ __launch_bounds__(384) void enc2_k(const int* __restrict__ src, const int* __restrict__ srclen,
    const float* __restrict__ embed, const float* __restrict__ wtih, const float* __restrict__ wthh,
    const float* __restrict__ bih, const float* __restrict__ bhh, float* sc, int t){
  int ic = blockIdx.x;      // i-chunk 0..7
  int b  = blockIdx.y;      // batch 0..15
  int tid = threadIdx.x;
  int p = tid >> 6;         // gate plane 0..5
  int il = tid & 63;
  int i = ic*64 + il;
  __shared__ __align__(16) float e[512];
  __shared__ __align__(16) float h[512];
  __shared__ float gsh[6][64];
  const float* hsrc = sc + HST_O + (t&1)*B*H + b*H;
  float* hdst = sc + HST_O + ((t&1)^1)*B*H + b*H;
  int tok = src[t*B + b];
  for (int u = tid; u < 512; u += 384){
    e[u] = embed[(long long)tok*E + u];
    h[u] = hsrc[u];
  }
  __syncthreads();
  float acc = 0.0f;
  if (p < 3){
    const float* w = wtih + p*512 + i;
    for (int k=0;k<512;k++) acc += e[k]*w[(long long)k*1536];
  } else {
    const float* w = wthh + (p-3)*512 + i;
    for (int k=0;k<512;k++) acc += h[k]*w[(long long)k*1536];
  }
  gsh[p][il] = acc;
  __syncthreads();
  if (tid < 64){
    int ii = ic*64 + tid;
    float r = sigm(gsh[0][tid] + bih[ii] + gsh[3][tid] + bhh[ii]);
    float z = sigm(gsh[1][tid] + bih[512+ii] + gsh[4][tid] + bhh[512+ii]);
    float nn = tanhf(gsh[2][tid] + bih[1024+ii] + r*(gsh[5][tid] + bhh[1024+ii]));
    float hnew = (1.0f - z)*nn + z*h[ii];
    float hout = (t < srclen[b]) ? hnew : h[ii];
    hdst[ii] = hout;
    sc[ENC_O + ((long long)t*B + b)*H + ii] = hout;
  }
}

// ---------------- bridge: write group-base rows of HN0 ----------------
__global__ __launch_bounds__(256) void bridge2_k(const float* __restrict__ wtb, const float* __restrict__ bb, float* sc){
  int b = blockIdx.x; int tid = threadIdx.x;
  __shared__ __align__(16) float hf[512];
  const float* hsrc = sc + HST_O + (S&1)*B*H + b*H;
  ((float2*)hf)[tid] = ((const float2*)hsrc)[tid];
  __syncthreads();
  for (int ii=0; ii<2; ii++){
    int i = tid + ii*256;
    float acc = bb[i];
    for (int k=0;k<512;k++) acc += hf[k]*wtb[(long long)k*512 + i];
    sc[HN0_O + (long long)(b*8)*H + i] = tanhf(acc);
  }
}

// ---------------- decoder GRU + beam(t-1) fused ----------------
// grid (8 i-chunks, 16 groups), 256 threads. h_prev identical across a group's
// 8 beams (reference's flat_offsets broadcast) -> Whh side computed once (wave 0).
__global__ __launch_bounds__(256) void grub_k(const float* __restrict__ embed,
    const float* __restrict__ wtih, const float* __restrict__ wthh,
    const float* __restrict__ bih, const float* __restrict__ bhh,
    float* sc, int t){
  int ic = blockIdx.x, g = blockIdx.y;
  int tid = threadIdx.x, il = tid & 63, wv = tid >> 6;
  int i = ic*64 + il;
  __shared__ __align__(16) float e8[8][512];
  __shared__ __align__(16) float hsh[512];
  __shared__ float hgr[64], hgz[64], hgn[64];
  __shared__ float tksc_s[64]; __shared__ int tkix_s[64];
  __shared__ float bsum[8]; __shared__ int eold[8];
  __shared__ float totL[64], curL[64];
  __shared__ int selp[8], ntok[8], nend[8]; __shared__ float nsc[8];

  if (t == 1){
    if (tid < 8) ntok[tid] = SOS;
  } else {
    int bt = t - 1;                 // beam step being applied
    int pr = t & 1;                 // read parity  (state after beam(t-2))
    int pw = bt & 1;                // write parity (state after beam(t-1))
    const float* bsc = sc + (pr ? BS1_O : BS0_O);
    const int* endr = (const int*)(sc + (pr ? END1_O : END0_O));
    if (tid < 64){
      tksc_s[tid] = sc[TKSC_O + g*64 + tid];
      tkix_s[tid] = ((const int*)(sc + TKIX_O))[g*64 + tid];
    }
    if (tid < 8){
      float tp = 0;
      for (int u=0; u<T; u++) tp += bsc[u*N + g*8 + tid];
      bsum[tid] = tp;
      eold[tid] = endr[g*8 + tid];
    }
    __syncthreads();
    if (tid < 64){
      int k = tid >> 3, j = tid & 7;
      float scv = tksc_s[tid];
      if (bt > 1) scv -= DD * (float)j;
      float fin = eold[k] ? (-scv + (j==0 ? 0.0f : FNEG)) : 0.0f;
      totL[tid] = (scv + bsum[k]) + fin;   // ((tk_sc+total)+fin) as in ref
      curL[tid] = scv + fin;
    }
    __syncthreads();
    if (tid == 0){
      for (int q=0;q<8;q++){
        int best = 0; float bv = totL[0];
        for (int c=1;c<64;c++) if (totL[c] > bv){ bv = totL[c]; best = c; }
        int p = best >> 3;
        int en = eold[p];
        int lt = en ? PAD : tkix_s[best];
        selp[q] = p; ntok[q] = lt;
        nsc[q] = (lt != PAD) ? curL[best] : 0.0f;
        nend[q] = (en || lt == EOS) ? 1 : 0;
        totL[best] = -INFINITY;
      }
    }
    __syncthreads();
    if (ic == 0){  // persist state for next step (opposite-parity buffers -> no race)
      const int* tokc; int* tokn; const float* bsr; float* bsn;
      if (pr){ tokc=(const int*)(sc+TOK1_O); bsr=sc+BS1_O; tokn=(int*)(sc+TOK0_O); bsn=(float*)(sc+BS0_O); }
      else   { tokc=(const int*)(sc+TOK0_O); bsr=sc+BS0_O; tokn=(int*)(sc+TOK1_O); bsn=(float*)(sc+BS1_O); }
      for (int u=tid; u<T*8; u+=256){
        int tp2 = u>>3, jp = u&7;
        if (tp2 == bt) continue;
        int p = selp[jp];
        tokn[tp2*N + g*8 + jp] = tokc[tp2*N + g*8 + p];
        bsn[tp2*N + g*8 + jp]  = bsr[tp2*N + g*8 + p];
      }
      if (tid < 8){
        tokn[bt*N + g*8 + tid] = ntok[tid];
        bsn[bt*N + g*8 + tid]  = nsc[tid];
        ((int*)(sc + (pw ? END1_O : END0_O)))[g*8 + tid] = nend[tid];
      }
    }
  }
  __syncthreads();
  // stage embeddings (per beam) + shared previous hidden (group-base row)
  const float* hr_ = sc + (((t-1)&1) ? HN1_O : HN0_O) + (long long)(g*8)*H;
  for (int u=tid; u<8*128; u+=256){
    int r = u>>7, c = u&127;
    ((float4*)e8[r])[c] = ((const float4*)(embed + (long long)ntok[r]*E))[c];
  }
  if (tid < 128) ((float4*)hsh)[tid] = ((const float4*)hr_)[tid];
  __syncthreads();
  int n0 = wv*2, n1 = wv*2+1;
  float a0r=0,a0z=0,a0n=0,a1r=0,a1z=0,a1n=0,h_r=0,h_z=0,h_n=0;
  for (int k=0;k<512;k++){
    const float* wk = wtih + (long long)k*1536;
    float wr=wk[i], wz=wk[512+i], wn=wk[1024+i];
    float e0=e8[n0][k], e1=e8[n1][k];
    a0r+=e0*wr; a0z+=e0*wz; a0n+=e0*wn;
    a1r+=e1*wr; a1z+=e1*wz; a1n+=e1*wn;
    if (wv==0){
      const float* uk = wthh + (long long)k*1536;
      float hv = hsh[k];
      h_r += hv*uk[i]; h_z += hv*uk[512+i]; h_n += hv*uk[1024+i];
    }
  }
  if (wv==0){ hgr[il]=h_r; hgz[il]=h_z; hgn[il]=h_n; }
  __syncthreads();
  float br=bih[i], bz=bih[512+i], bn=bih[1024+i];
  float cr=bhh[i], cz=bhh[512+i], cn=bhh[1024+i];
  float hR=hgr[il], hZ=hgz[il], hN=hgn[il], hprev=hsh[i];
  float* hw = sc + ((t&1) ? HN1_O : HN0_O);
  {
    float r = sigm(a0r+br+hR+cr);
    float z = sigm(a0z+bz+hZ+cz);
    float nn = tanhf(a0n+bn + r*(hN+cn));
    hw[(long long)(g*8+n0)*H + i] = (1.0f-z)*nn + z*hprev;
  }
  {
    float r = sigm(a1r+br+hR+cr);
    float z = sigm(a1z+bz+hZ+cz);
    float nn = tanhf(a1n+bn + r*(hN+cn));
    hw[(long long)(g*8+n1)*H + i] = (1.0f-z)*nn + z*hprev;
  }
}

// ---------------- q = h@attW^T ; attention ; o = tanh([h,ctx]@combW^T+b) fused, per row ----------------
__global__ __launch_bounds__(256) void qac_k(const int* __restrict__ srclen,
    const float* __restrict__ wta, const float* __restrict__ wtc, const float* __restrict__ cb,
    float* sc, int t){
  int n = blockIdx.x, g = n >> 3;
  int tid = threadIdx.x, lane = tid & 63, wave = tid >> 6;
  __shared__ __align__(16) float h[512];
  __shared__ __align__(16) float q[512];
  __shared__ __align__(16) float cx[512];
  __shared__ float al[64];
  const float* hn = sc + ((t&1) ? HN1_O : HN0_O) + (long long)n*H;
  if (tid < 128) ((float4*)h)[tid] = ((const float4*)hn)[tid];
  __syncthreads();
  for (int ii=0; ii<2; ii++){
    int i = tid + ii*256;
    float a = 0;
    for (int k=0;k<512;k++) a += h[k]*wta[(long long)k*512 + i];
    q[i] = a;
  }
  __syncthreads();
  const float* enc = sc + ENC_O;
  for (int s = wave; s < S; s += 4){
    const float* er = enc + ((long long)s*B + g)*H;
    float p = 0;
    #pragma unroll
    for (int j=0;j<8;j++) p += q[lane + 64*j]*er[lane + 64*j];
    #pragma unroll
    for (int off=32; off; off>>=1) p += __shfl_xor(p, off, 64);
    if (lane==0) al[s] = p;
  }
  __syncthreads();
  if (wave==0){
    int len = srclen[g];
    float v = (lane < S && lane < len) ? al[lane] : -1e9f;
    float m = v;
    #pragma unroll
    for (int off=32; off; off>>=1) m = fmaxf(m, __shfl_xor(m, off, 64));
    float ee = (lane < S) ? expf(v - m) : 0.0f;
    float ssum = ee;
    #pragma unroll
    for (int off=32; off; off>>=1) ssum += __shfl_xor(ssum, off, 64);
    if (lane < S) al[lane] = ee/ssum;
  }
  __syncthreads();
  for (int ii=0; ii<2; ii++){
    int i = tid + ii*256;
    float a = 0;
    for (int s=0;s<S;s++) a += al[s]*enc[((long long)s*B+g)*H + i];
    cx[i] = a;
  }
  __syncthreads();
  for (int ii=0; ii<2; ii++){
    int i = tid + ii*256;
    float a = cb[i];
    for (int k=0;k<512;k++) a += h[k]*wtc[(long long)k*512 + i];
    for (int k=0;k<512;k++) a += cx[k]*wtc[(long long)(512+k)*512 + i];
    sc[OVEC_O + (long long)n*H + i] = tanhf(a);
  }
}

// ---------------- logits = o @ out_W^T + out_b (round-3 proven) ----------------
__global__ __launch_bounds__(256) void logits_k(const float* __restrict__ wto, const float* __restrict__ ob, float* sc){
  int v = blockIdx.x*1024 + threadIdx.x*4;
  int nb = blockIdx.y*16;
  __shared__ __align__(16) float o16[16][512];
  for (int u = threadIdx.x; u < 16*128; u += 256){
    int r = u>>7, c = u&127;
    ((float4*)o16[r])[c] = ((const float4*)(sc + OVEC_O + (long long)(nb + r)*H))[c];
  }
  __syncthreads();
  if (v >= V) return;
  float acc[16][4] = {};
  const float* wp = wto + v;
  for (int k=0;k<512;k+=4){
    float4 w0 = *((const float4*)(wp + (long long)(k+0)*V));
    float4 w1 = *((const float4*)(wp + (long long)(k+1)*V));
    float4 w2 = *((const float4*)(wp + (long long)(k+2)*V));
    float4 w3 = *((const float4*)(wp + (long long)(k+3)*V));
    #pragma unroll
    for (int j=0;j<16;j++){
      float4 o = *((const float4*)&o16[j][k]);
      acc[j][0] += o.x*w0.x + o.y*w1.x + o.z*w2.x + o.w*w3.x;
      acc[j][1] += o.x*w0.y + o.y*w1.y + o.z*w2.y + o.w*w3.y;
      acc[j][2] += o.x*w0.z + o.y*w1.z + o.z*w2.z + o.w*w3.z;
      acc[j][3] += o.x*w0.w + o.y*w1.w + o.z*w2.w + o.w*w3.w;
    }
  }
  float4 bbv = *((const float4*)(ob + v));
  #pragma unroll
  for (int j=0;j<16;j++){
    float4 r;
    r.x = acc[j][0]+bbv.x; r.y = acc[j][1]+bbv.y; r.z = acc[j][2]+bbv.z; r.w = acc[j][3]+bbv.w;
    *((float4*)(sc + LOGITS_O + (long long)(nb+j)*V + v)) = r;
  }
}

// ---------------- per-row logsumexp + top-8 (round-3 proven) ----------------
__global__ __launch_bounds__(256) void topk_k(float* sc, int t){
  int n = blockIdx.x, tid = threadIdx.x;
  const float4* row4 = (const float4*)(sc + LOGITS_O + (long long)n*V);
  __shared__ float rv[256];
  __shared__ float mv[256][8];
  __shared__ int   mi[256][8];
  float lm = -INFINITY;
  for (int u = tid; u < V/4; u += 256){
    float4 x = row4[u];
    lm = fmaxf(lm, fmaxf(fmaxf(x.x,x.y), fmaxf(x.z,x.w)));
  }
  rv[tid] = lm; __syncthreads();
  for (int s2=128; s2; s2>>=1){ if (tid<s2) rv[tid]=fmaxf(rv[tid],rv[tid+s2]); __syncthreads(); }
  float rmax = rv[0]; __syncthreads();
  float tv[8]; int ti[8];
  #pragma unroll
  for (int j=0;j<8;j++){ tv[j] = -INFINITY; ti[j] = V; }
  float ls = 0;
  for (int u = tid; u < V/4; u += 256){
    float4 x = row4[u];
    ls += expf(x.x-rmax)+expf(x.y-rmax)+expf(x.z-rmax)+expf(x.w-rmax);
    #pragma unroll
    for (int c=0;c<4;c++){
      int idx = u*4+c;
      float val = (c==0)?x.x:(c==1)?x.y:(c==2)?x.z:x.w;
      bool masked = (idx==UNK) || (idx==EOS && t<=MIN_LEN);
      if (!masked && val > tv[7]){
        tv[7] = val; ti[7] = idx;
        #pragma unroll
        for (int j=7;j>0;j--){
          if (tv[j] > tv[j-1]){
            float tf=tv[j]; tv[j]=tv[j-1]; tv[j-1]=tf;
            int tii=ti[j]; ti[j]=ti[j-1]; ti[j-1]=tii;
          }
        }
      }
    }
  }
  rv[tid] = ls;
  #pragma unroll
  for (int j=0;j<8;j++){ mv[tid][j]=tv[j]; mi[tid][j]=ti[j]; }
  __syncthreads();
  for (int s2=128; s2; s2>>=1){ if (tid<s2) rv[tid]+=rv[tid+s2]; __syncthreads(); }
  float lsum = logf(rv[0]);
  for (int s2=128; s2; s2>>=1){
    if (tid < s2){
      float ra[8]; int ri_[8];
      int pa=0, pb=0;
      #pragma unroll
      for (int o=0;o<8;o++){
        float va = mv[tid][pa<8?pa:7];   int xa = mi[tid][pa<8?pa:7];
        float vb = mv[tid+s2][pb<8?pb:7]; int xb = mi[tid+s2][pb<8?pb:7];
        bool ava = (pa<8), avb = (pb<8);
        bool ta;
        if (!ava) ta = false;
        else if (!avb) ta = true;
        else ta = (va > vb) || (va == vb && xa < xb);
        ra[o] = ta ? va : vb; ri_[o] = ta ? xa : xb;
        pa += ta ? 1 : 0; pb += ta ? 0 : 1;
      }
      #pragma unroll
      for (int o=0;o<8;o++){ mv[tid][o]=ra[o]; mi[tid][o]=ri_[o]; }
    }
    __syncthreads();
  }
  if (tid < 8){
    sc[TKSC_O + n*8 + tid] = (mv[0][tid] - rmax) - lsum;
    ((int*)(sc + TKIX_O))[n*8 + tid] = mi[0][tid];
  }
}

// ---------------- final beam(T-1) + emit ----------------
__global__ __launch_bounds__(256) void final_k(float* out, float* sc){
  int g = blockIdx.x, tid = threadIdx.x;
  __shared__ float tksc_s[64]; __shared__ int tkix_s[64];
  __shared__ float bsum[8]; __shared__ int eold[8];
  __shared__ float totL[64], curL[64];
  __shared__ int selp[8], ntok[8]; __shared__ float nsc[8];
  const float* bsc = sc + BS0_O;            // beam(39) reads parity 0
  const int* endr = (const int*)(sc + END0_O);
  const int* tokc = (const int*)(sc + TOK0_O);
  if (tid < 64){
    tksc_s[tid] = sc[TKSC_O + g*64 + tid];
    tkix_s[tid] = ((const int*)(sc + TKIX_O))[g*64 + tid];
  }
  if (tid < 8){
    float tp = 0;
    for (int u=0; u<T; u++) tp += bsc[u*N + g*8 + tid];
    bsum[tid] = tp;
    eold[tid] = endr[g*8 + tid];
  }
  __syncthreads();
  if (tid < 64){
    int k = tid >> 3, j = tid & 7;
    float scv = tksc_s[tid] - DD * (float)j;   // bt=39 > 1 always
    float fin = eold[k] ? (-scv + (j==0 ? 0.0f : FNEG)) : 0.0f;
    totL[tid] = (scv + bsum[k]) + fin;
    curL[tid] = scv + fin;
  }
  __syncthreads();
  if (tid == 0){
    for (int q=0;q<8;q++){
      int best = 0; float bv = totL[0];
      for (int c=1;c<64;c++) if (totL[c] > bv){ bv = totL[c]; best = c; }
      int p = best >> 3;
      int en = eold[p];
      int lt = en ? PAD : tkix_s[best];
      selp[q] = p; ntok[q] = lt;
      nsc[q] = (lt != PAD) ? curL[best] : 0.0f;
      totL[best] = -INFINITY;
    }
  }
  __syncthreads();
  for (int u = tid; u < T*8; u += 256){
    int tp2 = u >> 3, jp = u & 7;
    int p = selp[jp];
    float tokv, bsv;
    if (tp2 == T-1){ tokv = (float)ntok[jp]; bsv = nsc[jp]; }
    else { tokv = (float)tokc[tp2*N + g*8 + p]; bsv = bsc[tp2*N + g*8 + p]; }
    out[TOK_OUT_OFF + tp2*N + g*8 + jp] = tokv;
    out[BS_OUT_OFF  + tp2*N + g*8 + jp] = bsv;
  }
}

extern "C" void kernel_launch(void* const* d_in, const int* in_sizes, int n_in,
                              void* d_out, int out_size, void* d_ws, size_t ws_size,
                              hipStream_t stream){
  const int*   src    = (const int*)d_in[0];
  const int*   srclen = (const int*)d_in[1];
  const float* embed  = (const float*)d_in[2];
  const float* eWih   = (const float*)d_in[3];
  const float* eWhh   = (const float*)d_in[4];
  const float* ebih   = (const float*)d_in[5];
  const float* ebhh   = (const float*)d_in[6];
  const float* brW    = (const float*)d_in[7];
  const float* brb    = (const float*)d_in[8];
  const float* dWih   = (const float*)d_in[9];
  const float* dWhh   = (const float*)d_in[10];
  const float* dbih   = (const float*)d_in[11];
  const float* dbhh   = (const float*)d_in[12];
  const float* attW   = (const float*)d_in[13];
  const float* cmbW   = (const float*)d_in[14];
  const float* cmbb   = (const float*)d_in[15];
  const float* outW   = (const float*)d_in[16];
  const float* outb   = (const float*)d_in[17];
  float* sc = (float*)d_out;

  tr_k<<<dim3(16,48),256,0,stream>>>(eWih, sc+WTEIH_O, 1536, 512);
  tr_k<<<dim3(16,48),256,0,stream>>>(eWhh, sc+WTEHH_O, 1536, 512);
  tr_k<<<dim3(16,48),256,0,stream>>>(dWih, sc+WTDIH_O, 1536, 512);
  tr_k<<<dim3(16,48),256,0,stream>>>(dWhh, sc+WTDHH_O, 1536, 512);
  tr_k<<<dim3(16,16),256,0,stream>>>(attW, sc+WTATT_O, 512, 512);
  tr_k<<<dim3(32,16),256,0,stream>>>(cmbW, sc+WTCMB_O, 512, 1024);
  tr_k<<<dim3(16,16),256,0,stream>>>(brW,  sc+WTBRG_O, 512, 512);
  tr_k<<<dim3(16,1000),256,0,stream>>>(outW, sc+WTOUT_O, 32000, 512);
  init_k<<<64,256,0,stream>>>(sc);

  for (int t=0; t<S; t++)
    enc2_k<<<dim3(8,16),384,0,stream>>>(src, srclen, embed, sc+WTEIH_O, sc+WTEHH_O, ebih, ebhh, sc, t);
  bridge2_k<<<16,256,0,stream>>>(sc+WTBRG_O, brb, sc);

  for (int t=1; t<T; t++){
    grub_k<<<dim3(8,16),256,0,stream>>>(embed, sc+WTDIH_O, sc+WTDHH_O, dbih, dbhh, sc, t);
    qac_k<<<128,256,0,stream>>>(srclen, sc+WTATT_O, sc+WTCMB_O, cmbb, sc, t);
    logits_k<<<dim3(32,8),256,0,stream>>>(sc+WTOUT_O, outb, sc);
    topk_k<<<128,256,0,stream>>>(sc, t);
  }

  final_k<<<16,256,0,stream>>>((float*)d_out, sc);
  hipMemsetAsync(d_out, 0, (size_t)PROBS_ELEMS*4, stream);
}

// Round 8
// 13082.903 us; speedup vs baseline: 3.3970x; 1.4850x over previous
//
#include <hip/hip_runtime.h>

#define DEVFN __device__ __forceinline__

constexpr int V=32000, E=512, H=512, B=16, K=8, S=50, T=40, N=128;
constexpr int SOS=2, EOS=3, UNK=0, PAD=1, MIN_LEN=3;
constexpr float DD=0.1f;
constexpr float FNEG=-1e20f;

constexpr long long PROBS_ELEMS = 163840000LL; // T*N*V
constexpr int TOK_OUT_OFF = 163840000;
constexpr int BS_OUT_OFF  = 163845120;

// scratch offsets (floats) inside d_out's probs region (re-zeroed at the end)
constexpr int LOGITS_O = 0;          // N*V
constexpr int WTOUT_O  = 4200000;    // 512*32000 transposed
constexpr int WTEIH_O  = 20600000;   // [512][1536] transposed
constexpr int WTEHH_O  = 21400000;
constexpr int WTDIH_O  = 22200000;
constexpr int WTDHH_O  = 23000000;
constexpr int WTATT_O  = 23800000;   // [512][512] transposed
constexpr int WTCMB_O  = 24100000;   // [1024][512] transposed
constexpr int WTBRG_O  = 24700000;   // [512][512] transposed
constexpr int ENC_O    = 25000000;   // S*B*H
constexpr int HST_O    = 25500000;   // 2*B*H
constexpr int HID_O    = 25520000;   // N*H
constexpr int HNEW_O   = 25600000;   // N*H
constexpr int CTX_O    = 25680000;   // N*H
constexpr int OVEC_O   = 25760000;   // N*H
constexpr int QVEC_O   = 25840000;   // N*H
constexpr int TKSC_O   = 25920000;   // N*K
constexpr int TKIX_O   = 25930000;   // N*K ints
constexpr int TOK0_O   = 25940000;   // T*N ints
constexpr int TOK1_O   = 25950000;
constexpr int BS0_O    = 25960000;   // T*N floats
constexpr int BS1_O    = 25970000;
constexpr int END_O    = 25980000;   // N ints
constexpr int LTOK_O   = 25990000;   // N ints
constexpr int FLAG_O   = 25996000;   // 1 int (pack-verify sentinel)
// packed copies (diagnostic only this round)
constexpr int PKEIH_O  = 26000000;
constexpr int PKEHH_O  = 26800000;
constexpr int PKDIH_O  = 27600000;
constexpr int PKDHH_O  = 28400000;
constexpr int PKATT_O  = 29200000;
constexpr int PKCMB_O  = 29500000;
constexpr int PKBRG_O  = 30100000;

DEVFN float sigm(float x){ return 1.0f/(1.0f + expf(-x)); }

// ---------------- transpose: in[R][C] -> out[C][R] ----------------
__global__ void tr_k(const float* __restrict__ in, float* __restrict__ out, int R, int C){
  __shared__ float t[32][33];
  int bx = blockIdx.x, by = blockIdx.y;
  int x = threadIdx.x & 31, y0 = threadIdx.x >> 5;
  for (int yy = y0; yy < 32; yy += 8){
    t[yy][x] = in[(long long)(by*32+yy)*C + bx*32 + x];
  }
  __syncthreads();
  for (int yy = y0; yy < 32; yy += 8){
    out[(long long)(bx*32+yy)*R + by*32 + x] = t[x][yy];
  }
}

// ---------------- pack: in[I][K] -> out[(k4*I + i)*4 + s] = in[i][4*k4+s] ----------------
__global__ void pack_k(const float* __restrict__ in, float* __restrict__ out, int I, int Kc){
  int idx = blockIdx.x*256 + threadIdx.x;
  int total = I*(Kc>>2);
  if (idx >= total) return;
  int k4 = idx / I;
  int i  = idx - k4*I;
  float4 v = *((const float4*)(in + (long long)i*Kc + 4*k4));
  *((float4*)(out + ((long long)k4*I + i)*4)) = v;
}

// ---------------- pack verify: orig[i][k] vs packed ----------------
__global__ void packchk_k(const float* __restrict__ orig, const float* __restrict__ packed,
                          int I, int Kc, int* flag){
  long long idx = (long long)blockIdx.x*256 + threadIdx.x;
  long long total = (long long)I*Kc;
  if (idx >= total) return;
  int i = (int)(idx / Kc); int k = (int)(idx - (long long)i*Kc);
  float a = orig[idx];
  float b = packed[((long long)(k>>2)*I + i)*4 + (k&3)];
  if (a != b) atomicOr(flag, 16);
}

// ---------------- init ----------------
__global__ void init_k(float* sc){
  int idx = blockIdx.x*256 + threadIdx.x;
  int* tok0 = (int*)(sc + TOK0_O);
  float* bs0 = sc + BS0_O;
  if (idx < T*N){
    tok0[idx] = (idx < N) ? SOS : 0;
    bs0[idx]  = (idx < N && (idx & 7)) ? FNEG : 0.0f;
  }
  if (idx < N){
    ((int*)(sc + END_O))[idx] = 0;
    ((int*)(sc + LTOK_O))[idx] = SOS;
  }
  if (idx < 2*B*H) sc[HST_O + idx] = 0.0f;
  if (idx == 0) ((int*)(sc + FLAG_O))[0] = 0;
}

// ---------------- zero the probs region ----------------
__global__ void zero_k(float4* __restrict__ p){
  long long idx = (long long)blockIdx.x*256 + threadIdx.x;
  long long stride = (long long)gridDim.x*256;
  const long long n4 = PROBS_ELEMS/4;
  float4 z; z.x=0.f; z.y=0.f; z.z=0.f; z.w=0.f;
  for (long long u = idx; u < n4; u += stride) p[u] = z;
}

// ---------------- encoder one step (round-6 proven; transposed weights) ----------------
__global__ __launch_bounds__(384) void enc2_k(const int* __restrict__ src, const int* __restrict__ srclen,
    const float* __restrict__ embed, const float* __restrict__ wtih, const float* __restrict__ wthh,
    const float* __restrict__ bih, const float* __restrict__ bhh, float* sc, int t){
  int ic = blockIdx.x;      // i-chunk 0..7
  int b  = blockIdx.y;      // batch 0..15
  int tid = threadIdx.x;
  int p = tid >> 6;         // gate plane 0..5
  int il = tid & 63;
  int i = ic*64 + il;
  __shared__ __align__(16) float e[512];
  __shared__ __align__(16) float h[512];
  __shared__ float gsh[6][64];
  const float* hsrc = sc + HST_O + (t&1)*B*H + b*H;
  float* hdst = sc + HST_O + ((t&1)^1)*B*H + b*H;
  int tok = src[t*B + b];
  for (int u = tid; u < 512; u += 384){
    e[u] = embed[(long long)tok*E + u];
    h[u] = hsrc[u];
  }
  __syncthreads();
  float acc = 0.0f;
  if (p < 3){
    const float* w = wtih + p*512 + i;
    for (int k=0;k<512;k++) acc += e[k]*w[(long long)k*1536];
  } else {
    const float* w = wthh + (p-3)*512 + i;
    for (int k=0;k<512;k++) acc += h[k]*w[(long long)k*1536];
  }
  gsh[p][il] = acc;
  __syncthreads();
  if (tid < 64){
    int ii = ic*64 + tid;
    float r = sigm(gsh[0][tid] + bih[ii] + gsh[3][tid] + bhh[ii]);
    float z = sigm(gsh[1][tid] + bih[512+ii] + gsh[4][tid] + bhh[512+ii]);
    float nn = tanhf(gsh[2][tid] + bih[1024+ii] + r*(gsh[5][tid] + bhh[1024+ii]));
    float hnew = (1.0f - z)*nn + z*h[ii];
    float hout = (t < srclen[b]) ? hnew : h[ii];
    hdst[ii] = hout;
    sc[ENC_O + ((long long)t*B + b)*H + ii] = hout;
  }
}

// ---------------- bridge + repeat K (round-3 proven) ----------------
__global__ __launch_bounds__(256) void bridge_k(const float* __restrict__ wtb, const float* __restrict__ bb, float* sc){
  int b = blockIdx.x; int tid = threadIdx.x;
  __shared__ __align__(16) float hf[512];
  const float* hsrc = sc + HST_O + (S&1)*B*H + b*H;
  ((float2*)hf)[tid] = ((const float2*)hsrc)[tid];
  __syncthreads();
  for (int ii=0; ii<2; ii++){
    int i = tid + ii*256;
    float acc = bb[i];
    for (int k=0;k<512;k++) acc += hf[k]*wtb[(long long)k*512 + i];
    float hb = tanhf(acc);
    for (int q=0;q<K;q++) sc[HID_O + ((long long)(b*K+q))*H + i] = hb;
  }
}

// ---------------- decoder GRU (round-3 proven) ----------------
__global__ __launch_bounds__(256) void grudec_k(const float* __restrict__ embed,
     const float* __restrict__ wtih, const float* __restrict__ wthh,
     const float* __restrict__ bih, const float* __restrict__ bhh, float* sc){
  int il = threadIdx.x & 63, sub = threadIdx.x >> 6;
  int i = blockIdx.x*64 + il;
  int nb = blockIdx.y*8;
  __shared__ __align__(16) float e8[8][512];
  __shared__ __align__(16) float hp8[8][512];
  const int* ltok = (const int*)(sc + LTOK_O);
  for (int u = threadIdx.x; u < 8*128; u += 256){
    int r = u >> 7, c = u & 127;
    ((float4*)e8[r])[c]  = ((const float4*)(embed + (long long)ltok[nb+r]*E))[c];
    ((float4*)hp8[r])[c] = ((const float4*)(sc + HID_O + (long long)(nb+r)*H))[c];
  }
  __syncthreads();
  int n0 = sub*2, n1 = sub*2+1;
  float a0r=0,a0z=0,a0n=0,h0r=0,h0z=0,h0n=0;
  float a1r=0,a1z=0,a1n=0,h1r=0,h1z=0,h1n=0;
  for (int k=0;k<512;k++){
    const float* wi = wtih + (long long)k*1536;
    const float* wh = wthh + (long long)k*1536;
    float wr=wi[i], wz=wi[512+i], wn=wi[1024+i];
    float ur=wh[i], uz=wh[512+i], un=wh[1024+i];
    float e0=e8[n0][k], e1=e8[n1][k], p0=hp8[n0][k], p1=hp8[n1][k];
    a0r+=e0*wr; a0z+=e0*wz; a0n+=e0*wn; h0r+=p0*ur; h0z+=p0*uz; h0n+=p0*un;
    a1r+=e1*wr; a1z+=e1*wz; a1n+=e1*wn; h1r+=p1*ur; h1z+=p1*uz; h1n+=p1*un;
  }
  float br=bih[i], bz=bih[512+i], bn=bih[1024+i];
  float cr=bhh[i], cz=bhh[512+i], cn=bhh[1024+i];
  {
    float r = sigm(a0r+br+h0r+cr);
    float z = sigm(a0z+bz+h0z+cz);
    float nn = tanhf(a0n+bn + r*(h0n+cn));
    sc[HNEW_O + (long long)(nb+n0)*H + i] = (1.0f-z)*nn + z*hp8[n0][i];
  }
  {
    float r = sigm(a1r+br+h1r+cr);
    float z = sigm(a1z+bz+h1z+cz);
    float nn = tanhf(a1n+bn + r*(h1n+cn));
    sc[HNEW_O + (long long)(nb+n1)*H + i] = (1.0f-z)*nn + z*hp8[n1][i];
  }
}

// ---------------- q = h_new @ attn_W^T (round-3 proven) ----------------
__global__ __launch_bounds__(256) void qgemm_k(const float* __restrict__ wta, float* sc){
  int il = threadIdx.x & 63, sub = threadIdx.x >> 6;
  int i = blockIdx.x*64 + il;
  int nb = blockIdx.y*8;
  __shared__ __align__(16) float hn8[8][512];
  for (int u = threadIdx.x; u < 8*128; u += 256){
    int r = u>>7, c = u&127;
    ((float4*)hn8[r])[c] = ((const float4*)(sc + HNEW_O + (long long)(nb+r)*H))[c];
  }
  __syncthreads();
  int n0 = sub*2, n1 = n0+1;
  float a0=0, a1=0;
  for (int k=0;k<512;k++){
    float w = wta[(long long)k*512 + i];
    a0 += hn8[n0][k]*w; a1 += hn8[n1][k]*w;
  }
  sc[QVEC_O + (long long)(nb+n0)*H + i] = a0;
  sc[QVEC_O + (long long)(nb+n1)*H + i] = a1;
}

// ---------------- attention (round-3 proven) ----------------
__global__ __launch_bounds__(256) void att_k(const int* __restrict__ srclen, float* sc){
  int n = blockIdx.x; int g = n >> 3;
  int tid = threadIdx.x, lane = tid & 63, wave = tid >> 6;
  __shared__ __align__(16) float ql[512];
  __shared__ float al[64];
  if (tid < 128) ((float4*)ql)[tid] = ((const float4*)(sc + QVEC_O + (long long)n*H))[tid];
  __syncthreads();
  const float* enc = sc + ENC_O;
  for (int s = wave; s < S; s += 4){
    const float* er = enc + ((long long)s*B + g)*H;
    float p = 0;
    #pragma unroll
    for (int j=0;j<8;j++) p += ql[lane + 64*j]*er[lane + 64*j];
    #pragma unroll
    for (int off=32; off; off>>=1) p += __shfl_xor(p, off, 64);
    if (lane==0) al[s] = p;
  }
  __syncthreads();
  if (wave==0){
    int len = srclen[g];
    float v = (lane < S && lane < len) ? al[lane] : -1e9f;
    float m = v;
    #pragma unroll
    for (int off=32; off; off>>=1) m = fmaxf(m, __shfl_xor(m, off, 64));
    float ee = (lane < S) ? expf(v - m) : 0.0f;
    float ssum = ee;
    #pragma unroll
    for (int off=32; off; off>>=1) ssum += __shfl_xor(ssum, off, 64);
    if (lane < S) al[lane] = ee/ssum;
  }
  __syncthreads();
  for (int ii=0; ii<2; ii++){
    int i = tid + ii*256;
    float acc = 0;
    for (int s=0;s<S;s++) acc += al[s]*enc[((long long)s*B+g)*H + i];
    sc[CTX_O + (long long)n*H + i] = acc;
  }
}

// ---------------- comb (round-3 proven) ----------------
__global__ __launch_bounds__(256) void comb_k(const float* __restrict__ wtc, const float* __restrict__ cb, float* sc){
  int il = threadIdx.x & 63, sub = threadIdx.x >> 6;
  int i = blockIdx.x*64 + il;
  int nb = blockIdx.y*8;
  __shared__ __align__(16) float hn8[8][512];
  __shared__ __align__(16) float cx8[8][512];
  for (int u = threadIdx.x; u < 8*128; u += 256){
    int r = u>>7, c = u&127;
    ((float4*)hn8[r])[c] = ((const float4*)(sc + HNEW_O + (long long)(nb+r)*H))[c];
    ((float4*)cx8[r])[c] = ((const float4*)(sc + CTX_O + (long long)(nb+r)*H))[c];
  }
  __syncthreads();
  int n0 = sub*2, n1 = n0+1;
  float a0=cb[i], a1=cb[i];
  for (int k=0;k<512;k++){
    float w = wtc[(long long)k*512 + i];
    a0 += hn8[n0][k]*w; a1 += hn8[n1][k]*w;
  }
  for (int k=0;k<512;k++){
    float w = wtc[(long long)(512+k)*512 + i];
    a0 += cx8[n0][k]*w; a1 += cx8[n1][k]*w;
  }
  sc[OVEC_O + (long long)(nb+n0)*H + i] = tanhf(a0);
  sc[OVEC_O + (long long)(nb+n1)*H + i] = tanhf(a1);
}

// ---------------- logits (round-3 + register prefetch) ----------------
__global__ __launch_bounds__(256) void logits_k(const float* __restrict__ wto, const float* __restrict__ ob, float* sc){
  int v = blockIdx.x*1024 + threadIdx.x*4;
  int nb = blockIdx.y*16;
  __shared__ __align__(16) float o16[16][512];
  for (int u = threadIdx.x; u < 16*128; u += 256){
    int r = u>>7, c = u&127;
    ((float4*)o16[r])[c] = ((const float4*)(sc + OVEC_O + (long long)(nb + r)*H))[c];
  }
  __syncthreads();
  if (v >= V) return;
  float acc[16][4] = {};
  const float* wp = wto + v;
  float4 c0 = *((const float4*)(wp));
  float4 c1 = *((const float4*)(wp + V));
  float4 c2 = *((const float4*)(wp + 2LL*V));
  float4 c3 = *((const float4*)(wp + 3LL*V));
  for (int k=0;k<512;k+=4){
    float4 n0v=c0, n1v=c1, n2v=c2, n3v=c3;
    if (k < 508){
      const float* np_ = wp + (long long)(k+4)*V;
      n0v = *((const float4*)(np_));
      n1v = *((const float4*)(np_ + V));
      n2v = *((const float4*)(np_ + 2LL*V));
      n3v = *((const float4*)(np_ + 3LL*V));
    }
    #pragma unroll
    for (int j=0;j<16;j++){
      float4 o = *((const float4*)&o16[j][k]);
      acc[j][0] += o.x*c0.x + o.y*c1.x + o.z*c2.x + o.w*c3.x;
      acc[j][1] += o.x*c0.y + o.y*c1.y + o.z*c2.y + o.w*c3.y;
      acc[j][2] += o.x*c0.z + o.y*c1.z + o.z*c2.z + o.w*c3.z;
      acc[j][3] += o.x*c0.w + o.y*c1.w + o.z*c2.w + o.w*c3.w;
    }
    c0=n0v; c1=n1v; c2=n2v; c3=n3v;
  }
  float4 bbv = *((const float4*)(ob + v));
  #pragma unroll
  for (int j=0;j<16;j++){
    float4 r;
    r.x = acc[j][0]+bbv.x; r.y = acc[j][1]+bbv.y; r.z = acc[j][2]+bbv.z; r.w = acc[j][3]+bbv.w;
    *((float4*)(sc + LOGITS_O + (long long)(nb+j)*V + v)) = r;
  }
}

// ---------------- topk (round-3 proven) ----------------
__global__ __launch_bounds__(256) void topk_k(float* sc, int t){
  int n = blockIdx.x, tid = threadIdx.x;
  const float4* row4 = (const float4*)(sc + LOGITS_O + (long long)n*V);
  __shared__ float rv[256];
  __shared__ float mv[256][8];
  __shared__ int   mi[256][8];
  float lm = -INFINITY;
  for (int u = tid; u < V/4; u += 256){
    float4 x = row4[u];
    lm = fmaxf(lm, fmaxf(fmaxf(x.x,x.y), fmaxf(x.z,x.w)));
  }
  rv[tid] = lm; __syncthreads();
  for (int s2=128; s2; s2>>=1){ if (tid<s2) rv[tid]=fmaxf(rv[tid],rv[tid+s2]); __syncthreads(); }
  float rmax = rv[0]; __syncthreads();
  float tv[8]; int ti[8];
  #pragma unroll
  for (int j=0;j<8;j++){ tv[j] = -INFINITY; ti[j] = V; }
  float ls = 0;
  for (int u = tid; u < V/4; u += 256){
    float4 x = row4[u];
    ls += expf(x.x-rmax)+expf(x.y-rmax)+expf(x.z-rmax)+expf(x.w-rmax);
    #pragma unroll
    for (int c=0;c<4;c++){
      int idx = u*4+c;
      float val = (c==0)?x.x:(c==1)?x.y:(c==2)?x.z:x.w;
      bool masked = (idx==UNK) || (idx==EOS && t<=MIN_LEN);
      if (!masked && val > tv[7]){
        tv[7] = val; ti[7] = idx;
        #pragma unroll
        for (int j=7;j>0;j--){
          if (tv[j] > tv[j-1]){
            float tf=tv[j]; tv[j]=tv[j-1]; tv[j-1]=tf;
            int tii=ti[j]; ti[j]=ti[j-1]; ti[j-1]=tii;
          }
        }
      }
    }
  }
  rv[tid] = ls;
  #pragma unroll
  for (int j=0;j<8;j++){ mv[tid][j]=tv[j]; mi[tid][j]=ti[j]; }
  __syncthreads();
  for (int s2=128; s2; s2>>=1){ if (tid<s2) rv[tid]+=rv[tid+s2]; __syncthreads(); }
  float lsum = logf(rv[0]);
  for (int s2=128; s2; s2>>=1){
    if (tid < s2){
      float ra[8]; int ri_[8];
      int pa=0, pb=0;
      #pragma unroll
      for (int o=0;o<8;o++){
        float va = mv[tid][pa<8?pa:7];   int xa = mi[tid][pa<8?pa:7];
        float vb = mv[tid+s2][pb<8?pb:7]; int xb = mi[tid+s2][pb<8?pb:7];
        bool ava = (pa<8), avb = (pb<8);
        bool ta;
        if (!ava) ta = false;
        else if (!avb) ta = true;
        else ta = (va > vb) || (va == vb && xa < xb);
        ra[o] = ta ? va : vb; ri_[o] = ta ? xa : xb;
        pa += ta ? 1 : 0; pb += ta ? 0 : 1;
      }
      #pragma unroll
      for (int o=0;o<8;o++){ mv[tid][o]=ra[o]; mi[tid][o]=ri_[o]; }
    }
    __syncthreads();
  }
  if (tid < 8){
    sc[TKSC_O + n*8 + tid] = (mv[0][tid] - rmax) - lsum;
    ((int*)(sc + TKIX_O))[n*8 + tid] = mi[0][tid];
  }
}

// ---------------- beam (round-3 proven) ----------------
__global__ __launch_bounds__(64) void beam_k(float* sc, int t){
  int b = blockIdx.x, lane = threadIdx.x;
  const float* tksc = sc + TKSC_O;
  const int* tkix = (const int*)(sc + TKIX_O);
  int* endp = (int*)(sc + END_O);
  int* ltok = (int*)(sc + LTOK_O);
  const int* tokc; int* tokn; const float* bsc; float* bsn;
  if (t & 1){ tokc=(const int*)(sc+TOK0_O); tokn=(int*)(sc+TOK1_O); bsc=sc+BS0_O; bsn=sc+BS1_O; }
  else      { tokc=(const int*)(sc+TOK1_O); tokn=(int*)(sc+TOK0_O); bsc=sc+BS1_O; bsn=sc+BS0_O; }
  __shared__ int selp[8]; __shared__ int newtok[8]; __shared__ float newsc[8]; __shared__ int newend[8];
  if (lane == 0){
    float tot[64]; float cur[64]; int tix[64];
    for (int k=0;k<8;k++){
      float tp = 0;
      for (int u=0;u<T;u++) tp += bsc[u*N + b*8 + k];
      int ek = endp[b*8+k];
      for (int j=0;j<8;j++){
        float scv = tksc[(b*8+k)*8 + j];
        if (t > 1) scv -= DD * (float)j;
        float fin = ek ? (-scv + (j==0 ? 0.0f : FNEG)) : 0.0f;
        tot[k*8+j] = (scv + tp) + fin;
        cur[k*8+j] = scv + fin;
        tix[k*8+j] = tkix[(b*8+k)*8 + j];
      }
    }
    for (int q=0;q<8;q++){
      int best = 0; float bv = tot[0];
      for (int c=1;c<64;c++){
        if (tot[c] > bv){ bv = tot[c]; best = c; }
      }
      int p = best >> 3;
      int en = endp[b*8+p];
      int tk2 = tix[best];
      int lt = en ? PAD : tk2;
      selp[q] = p;
      newtok[q] = lt;
      newsc[q] = (lt != PAD) ? cur[best] : 0.0f;
      newend[q] = (en || lt == EOS) ? 1 : 0;
      tot[best] = -INFINITY;
    }
  }
  __syncthreads();
  for (int u = lane; u < T*8; u += 64){
    int tp2 = u >> 3, jp = u & 7;
    int p = selp[jp];
    tokn[tp2*N + b*8 + jp] = tokc[tp2*N + b*8 + p];
    bsn[tp2*N + b*8 + jp]  = bsc[tp2*N + b*8 + p];
  }
  __syncthreads();
  if (lane < 8){
    tokn[t*N + b*8 + lane] = newtok[lane];
    bsn[t*N + b*8 + lane]  = newsc[lane];
    ltok[b*8+lane] = newtok[lane];
    endp[b*8+lane] = newend[lane];
  }
  const float4* hsrc = (const float4*)(sc + HNEW_O + (long long)(b*8)*H);
  float4* hdst = (float4*)(sc + HID_O + (long long)(b*8)*H);
  for (int u = lane; u < 8*128; u += 64){
    int jp = u >> 7, c = u & 127;
    hdst[jp*128 + c] = hsrc[c];
  }
}

// ---------------- emit tokens + beam_scores (+pack sentinel) ----------------
__global__ void emit_k(float* out, float* sc){
  int idx = blockIdx.x*256 + threadIdx.x;
  if (idx < T*N){
    out[TOK_OUT_OFF + idx] = (float)(((const int*)(sc + TOK1_O))[idx]);
    out[BS_OUT_OFF + idx]  = sc[BS1_O + idx];
  }
  if (idx == 0){
    int f = ((const int*)(sc + FLAG_O))[0];
    if (f) out[TOK_OUT_OFF] = 1.0e6f + (float)f;
  }
}

extern "C" void kernel_launch(void* const* d_in, const int* in_sizes, int n_in,
                              void* d_out, int out_size, void* d_ws, size_t ws_size,
                              hipStream_t stream){
  const int*   src    = (const int*)d_in[0];
  const int*   srclen = (const int*)d_in[1];
  const float* embed  = (const float*)d_in[2];
  const float* eWih   = (const float*)d_in[3];
  const float* eWhh   = (const float*)d_in[4];
  const float* ebih   = (const float*)d_in[5];
  const float* ebhh   = (const float*)d_in[6];
  const float* brW    = (const float*)d_in[7];
  const float* brb    = (const float*)d_in[8];
  const float* dWih   = (const float*)d_in[9];
  const float* dWhh   = (const float*)d_in[10];
  const float* dbih   = (const float*)d_in[11];
  const float* dbhh   = (const float*)d_in[12];
  const float* attW   = (const float*)d_in[13];
  const float* cmbW   = (const float*)d_in[14];
  const float* cmbb   = (const float*)d_in[15];
  const float* outW   = (const float*)d_in[16];
  const float* outb   = (const float*)d_in[17];
  float* sc = (float*)d_out;

  tr_k<<<dim3(16,48),256,0,stream>>>(eWih, sc+WTEIH_O, 1536, 512);
  tr_k<<<dim3(16,48),256,0,stream>>>(eWhh, sc+WTEHH_O, 1536, 512);
  tr_k<<<dim3(16,48),256,0,stream>>>(dWih, sc+WTDIH_O, 1536, 512);
  tr_k<<<dim3(16,48),256,0,stream>>>(dWhh, sc+WTDHH_O, 1536, 512);
  tr_k<<<dim3(16,16),256,0,stream>>>(attW, sc+WTATT_O, 512, 512);
  tr_k<<<dim3(32,16),256,0,stream>>>(cmbW, sc+WTCMB_O, 512, 1024);
  tr_k<<<dim3(16,16),256,0,stream>>>(brW,  sc+WTBRG_O, 512, 512);
  tr_k<<<dim3(16,1000),256,0,stream>>>(outW, sc+WTOUT_O, 32000, 512);
  // diagnostic: pack + verify (does not feed the compute path)
  pack_k<<<768,256,0,stream>>>(eWih, sc+PKEIH_O, 1536, 512);
  pack_k<<<768,256,0,stream>>>(eWhh, sc+PKEHH_O, 1536, 512);
  pack_k<<<768,256,0,stream>>>(dWih, sc+PKDIH_O, 1536, 512);
  pack_k<<<768,256,0,stream>>>(dWhh, sc+PKDHH_O, 1536, 512);
  pack_k<<<256,256,0,stream>>>(attW, sc+PKATT_O, 512, 512);
  pack_k<<<512,256,0,stream>>>(cmbW, sc+PKCMB_O, 512, 1024);
  pack_k<<<256,256,0,stream>>>(brW,  sc+PKBRG_O, 512, 512);
  init_k<<<64,256,0,stream>>>(sc);
  {
    int* flag = (int*)(sc + FLAG_O);
    packchk_k<<<3072,256,0,stream>>>(eWih, sc+PKEIH_O, 1536, 512, flag);
    packchk_k<<<3072,256,0,stream>>>(eWhh, sc+PKEHH_O, 1536, 512, flag);
    packchk_k<<<3072,256,0,stream>>>(dWih, sc+PKDIH_O, 1536, 512, flag);
    packchk_k<<<3072,256,0,stream>>>(dWhh, sc+PKDHH_O, 1536, 512, flag);
    packchk_k<<<1024,256,0,stream>>>(attW, sc+PKATT_O, 512, 512, flag);
    packchk_k<<<2048,256,0,stream>>>(cmbW, sc+PKCMB_O, 512, 1024, flag);
    packchk_k<<<1024,256,0,stream>>>(brW,  sc+PKBRG_O, 512, 512, flag);
  }

  for (int t=0; t<S; t++)
    enc2_k<<<dim3(8,16),384,0,stream>>>(src, srclen, embed, sc+WTEIH_O, sc+WTEHH_O, ebih, ebhh, sc, t);
  bridge_k<<<16,256,0,stream>>>(sc+WTBRG_O, brb, sc);

  for (int t=1; t<T; t++){
    grudec_k<<<dim3(8,16),256,0,stream>>>(embed, sc+WTDIH_O, sc+WTDHH_O, dbih, dbhh, sc);
    qgemm_k<<<dim3(8,16),256,0,stream>>>(sc+WTATT_O, sc);
    att_k<<<128,256,0,stream>>>(srclen, sc);
    comb_k<<<dim3(8,16),256,0,stream>>>(sc+WTCMB_O, cmbb, sc);
    logits_k<<<dim3(32,8),256,0,stream>>>(sc+WTOUT_O, outb, sc);
    topk_k<<<128,256,0,stream>>>(sc, t);
    beam_k<<<16,64,0,stream>>>(sc, t);
  }

  emit_k<<<20,256,0,stream>>>((float*)d_out, sc);
  zero_k<<<2048,256,0,stream>>>((float4*)d_out);
}